// Round 7
// baseline (3404.833 us; speedup 1.0000x reference)
//
#include <hip/hip_runtime.h>

// Seq2seq LSTM (B=64, T=256, E=512, H=1024, V_TGT=64) on gfx950.
//   k1a: gather+convert A_bf16[16512][512]
//   k1w: W_lstm fp32 [1536][4096] -> WpermT bf16 [4096][1536] (col-permuted)
//   k1p: W_proj -> WprojT bf16 [64][1024]
//   k2 : Zx bf16 [16512][4096] = A @ Wx
//   k3 : persistent 256-WG recurrence.
//        - h flows through 512 WRITE-ONCE buffers: producers sc1-store (LLC),
//          consumers use PLAIN 16B loads -> per-XCD L2 sharing.
//        - W_h slice in VGPRs/AGPRs -> zero per-step ds_reads.
//        - 2D partition (WG = 16 batch rows x 16 units); h rows are
//          domain-disjoint -> the recurrence decomposes into 4 INDEPENDENT
//          sync domains (bg = w&3) of 64 WGs each (round 7).
//        - Round-7 barrier: leaderless finisher chain per domain. Arrivals
//          fetch_add 4 sub-lines (16 adds each, zero pollers); 16th arriver
//          adds to a super-line; its 4th arriver writes 2 go lines (<=32
//          pollers each). Removes the aggregator poll-detect stage of r6.
//   k4 : projection + softmax -> d_out fp32 [64][256][64]

typedef __attribute__((ext_vector_type(8))) short short8;        // bf16 frag
typedef __attribute__((ext_vector_type(4))) float f32x4;         // MFMA acc
typedef __attribute__((ext_vector_type(4))) float float4v;
typedef __attribute__((ext_vector_type(4))) unsigned short ushort4v;

#define MFMA16(A, B, C) __builtin_amdgcn_mfma_f32_16x16x32_bf16((A), (B), (C), 0, 0, 0)
#define WAIT_VM0() __builtin_amdgcn_s_waitcnt(0x0F70)   // vmcnt(0), ignore exp/lgkm
#define COMPILER_FENCE() asm volatile("" ::: "memory")

__device__ __forceinline__ unsigned short f2bf(float f) {
  union { float f; unsigned u; } v; v.f = f;
  unsigned r = (v.u + 0x7fffu + ((v.u >> 16) & 1u)) >> 16;   // RNE, no NaN in data
  return (unsigned short)r;
}
__device__ __forceinline__ float bf2f(unsigned short h) {
  union { unsigned u; float f; } v; v.u = ((unsigned)h) << 16;
  return v.f;
}
__device__ __forceinline__ float sigf(float x) { return 1.0f / (1.0f + __expf(-x)); }
__device__ __forceinline__ float tanhf_fast(float x) { return 1.0f - 2.0f / (1.0f + __expf(2.0f * x)); }

// Chain buffer C_t (h-state consumed at step t), t in 1..512.
//   t==1      : dedicated hbuf1 (128 KB)
//   2..256    : overlay dead Zx encoder region (t-2): byte off (t-2)*512KB
//   257..512  : dedicated decoder chain (also k4's input), 128 KB each
// Domain safety: domain d only ever touches rows r with (r&63)>>4 == d of any
// chain buffer / encoder Zx row-block -> all chain traffic is domain-disjoint.
__device__ __forceinline__ unsigned short*
chain_ptr(unsigned short* Zx, unsigned short* hbuf1, unsigned short* chainD, int t)
{
  if (t == 1)  return hbuf1;
  if (t < 257) return Zx + (size_t)(t - 2) * 262144;
  return chainD + (size_t)(t - 257) * 65536;
}

// ---------------------------------------------------------------- k1a
__global__ __launch_bounds__(128)
void k1a_gather(const int* __restrict__ tok_src,
                const float* __restrict__ emb_src,
                const float* __restrict__ emb_tgt,
                unsigned short* __restrict__ A)
{
  const int n = blockIdx.x;     // 0..16511
  const int i = threadIdx.x;    // 0..127, each does 4 elements
  float4v v = {0.f, 0.f, 0.f, 0.f};
  if (n < 16384) {
    const int b = n & 63, t = n >> 6;                 // row n = t*64 + b
    const int tk = tok_src[b * 256 + t];              // input_source[b][t]
    v = *(const float4v*)(emb_src + (size_t)tk * 512 + i * 4);
  } else if (n < 16448) {
    v = *(const float4v*)(emb_tgt + (size_t)(n - 16384) * 512 + i * 4);
  }
  ushort4v o;
  o.x = f2bf(v.x); o.y = f2bf(v.y); o.z = f2bf(v.z); o.w = f2bf(v.w);
  *(ushort4v*)(A + (size_t)n * 512 + i * 4) = o;
}

// ---------------------------------------------------------------- k1w
__global__ __launch_bounds__(256)
void k1w_perm(const float* __restrict__ W, unsigned short* __restrict__ WT)
{
  const int id = blockIdx.x * 256 + threadIdx.x;  // < 786432 = 4096 * 192
  const int n  = id & 4095;                        // permuted col
  const int k0 = (id >> 12) * 8;                   // 0..1528
  const int g = n & 3, u = (n >> 2) & 3, wq = n >> 4;
  const int oc = g * 1024 + 4 * wq + u;
  short8 o;
#pragma unroll
  for (int j = 0; j < 8; ++j)
    o[j] = (short)f2bf(W[(size_t)(k0 + j) * 4096 + oc]);
  *(short8*)(WT + (size_t)n * 1536 + k0) = o;
}

// ---------------------------------------------------------------- k1p
__global__ __launch_bounds__(256)
void k1p_perm(const float* __restrict__ W, unsigned short* __restrict__ WT)
{
  const int id = blockIdx.x * 256 + threadIdx.x;  // < 8192 = 64 * 128
  const int n  = id & 63;
  const int k0 = (id >> 6) * 8;
  short8 o;
#pragma unroll
  for (int j = 0; j < 8; ++j)
    o[j] = (short)f2bf(W[(size_t)(k0 + j) * 64 + n]);
  *(short8*)(WT + (size_t)n * 1024 + k0) = o;
}

// ---------------------------------------------------------------- k2
__global__ __launch_bounds__(256, 1)
void k2_gemm(const unsigned short* __restrict__ A,
             const unsigned short* __restrict__ BT,
             unsigned short* __restrict__ C)
{
  __shared__ __align__(16) unsigned short As[128 * 40];
  __shared__ __align__(16) unsigned short Bs[128 * 40];
  const int tid = threadIdx.x;
  const int n0 = blockIdx.x * 128;   // 32 blocks
  const int m0 = blockIdx.y * 128;   // 129 blocks
  const int wv = tid >> 6, lane = tid & 63;
  const int wr = wv & 1, wc = wv >> 1;
  const int q = lane >> 4, l15 = lane & 15;
  f32x4 acc[4][4];
#pragma unroll
  for (int a = 0; a < 4; ++a)
#pragma unroll
    for (int b = 0; b < 4; ++b)
      acc[a][b] = (f32x4){0.f, 0.f, 0.f, 0.f};

  for (int kt = 0; kt < 16; ++kt) {   // K = 512, BK = 32
    __syncthreads();
#pragma unroll
    for (int s = 0; s < 2; ++s) {
      const int ci = tid + s * 256;
      const int row = ci >> 2, kc = ci & 3;
      *(short8*)(&As[row * 40 + kc * 8]) =
          *(const short8*)(A + (size_t)(m0 + row) * 512 + kt * 32 + kc * 8);
      *(short8*)(&Bs[row * 40 + kc * 8]) =
          *(const short8*)(BT + (size_t)(n0 + row) * 1536 + kt * 32 + kc * 8);
    }
    __syncthreads();
    short8 af[4], bf[4];
#pragma unroll
    for (int i = 0; i < 4; ++i) {
      af[i] = *(const short8*)(&As[(wr * 64 + i * 16 + l15) * 40 + q * 8]);
      bf[i] = *(const short8*)(&Bs[(wc * 64 + i * 16 + l15) * 40 + q * 8]);
    }
#pragma unroll
    for (int mi = 0; mi < 4; ++mi)
#pragma unroll
      for (int ni = 0; ni < 4; ++ni)
        acc[mi][ni] = MFMA16(af[mi], bf[ni], acc[mi][ni]);
  }
#pragma unroll
  for (int mi = 0; mi < 4; ++mi)
#pragma unroll
    for (int ni = 0; ni < 4; ++ni)
#pragma unroll
      for (int i = 0; i < 4; ++i) {
        const int row = m0 + wr * 64 + mi * 16 + q * 4 + i;
        const int col = n0 + wc * 64 + ni * 16 + l15;
        C[(size_t)row * 4096 + col] = f2bf(acc[mi][ni][i]);
      }
}

// ---------------------------------------------------------------- k3
// 256 WGs x 256 threads, 512 steps. 4 independent domains (d = w&3).
// WG w: batch rows 16d..+15, units 16*(w>>2)..+15; wave v -> unit-quad
// Q = 4*(w>>2)+v. All 4 waves read the same 16 h-rows.
__global__ __launch_bounds__(256, 1)
void k3_rnn(unsigned short* __restrict__ Zx,
            const unsigned short* __restrict__ WT,
            const float* __restrict__ b_lstm,
            const int* __restrict__ tok_tgt,
            unsigned short* __restrict__ hbuf1,    // C_1 (128 KB)
            unsigned short* __restrict__ chainD,   // C_257..C_512 (32 MB)
            int* __restrict__ a1,                  // [513][4][4] sub arrival, 64B lines
            int* __restrict__ a2,                  // [513][4]    super arrival
            int* __restrict__ go)                  // [513][4][2] release flags
{
  __shared__ float ztile[4 * 16 * 17];             // per-wave 16x16 (+1 pad)
  __shared__ int s_dead;
  const int w = blockIdx.x;
  const int tid = threadIdx.x;
  const int wv = tid >> 6, lane = tid & 63;
  const int d  = w & 3;            // sync domain = batch group
  const int ug = w >> 2;           // unit group 0..63
  const int Q  = 4 * ug + wv;      // this wave's unit-quad (0..255)
  const int rbase = d * 16;
  const int j1 = ug >> 4;          // arrival sub-line 0..3 (16 adds each)
  const int g1 = ug >> 5;          // go line 0..1 (<=32 pollers each)

  // Gate-phase lane mapping: 64 lanes = 16 rows x 4 units.
  const int gr = lane >> 2, gu = lane & 3;
  const int rglob = rbase + gr;
  const float bias0 = b_lstm[4 * Q + gu];                  // i
  const float bias1 = b_lstm[1024 + 4 * Q + gu];           // j
  const float bias2 = b_lstm[2048 + 4 * Q + gu] + 1.0f;    // f + forget_bias
  const float bias3 = b_lstm[3072 + 4 * Q + gu];           // o
  float cst = 0.f;
  // MFMA-phase lane mapping.
  const int q = lane >> 4, m15 = lane & 15;
  const int arow = rbase + m15;
  float* const zt_w = &ztile[wv * 272];

  // Preload the wave's W_h B-frags: col Q*16+m15, k 512+kt*32+q*8.
  short8 Breg[32];
  {
    const unsigned short* wsrc = WT + (size_t)(Q * 16 + m15) * 1536 + 512 + q * 8;
#pragma unroll
    for (int kt = 0; kt < 32; ++kt)
      Breg[kt] = *(const short8*)(wsrc + kt * 32);
  }
  if (tid == 0) s_dead = 0;
  __syncthreads();

  for (int t = 0; t < 512; ++t) {
    // Prefetch x-contribution (overlaps the barrier wait).
    unsigned long long zx8;
    if (t < 256) {
      // Encoder Zx rows: sc1 (L1/L2-bypass) so overlaid chain reads stay safe.
      const size_t xrow = (size_t)(t * 64 + rglob);
      zx8 = __hip_atomic_load((const unsigned long long*)(Zx + xrow * 4096 + Q * 16 + gu * 4),
                              __ATOMIC_RELAXED, __HIP_MEMORY_SCOPE_AGENT);
    } else {
      // Decoder table rows 16384+tok: never overlaid -> normal (L2-hot) load.
      const size_t xrow = (size_t)(16384 + tok_tgt[rglob * 256 + (t - 256)]);
      zx8 = *(const unsigned long long*)(Zx + xrow * 4096 + Q * 16 + gu * 4);
    }

    // ---- Domain barrier-in: C_t rows of domain d fully published. ----
    if (t > 0) {
      if (tid == 0) {
        int spin = 0;
        while (__hip_atomic_load(&go[((t * 4 + d) * 2 + g1) * 16],
                                 __ATOMIC_RELAXED, __HIP_MEMORY_SCOPE_AGENT) == 0) {
          __builtin_amdgcn_s_sleep(1);
          if (++spin > (1 << 18)) { s_dead = 1; break; }
        }
      }
      COMPILER_FENCE();
      __syncthreads();
      if (s_dead) break;
    }

    // z_tile = h[16 rows][1024] @ Wh_slice[1024][16]; h via plain 16B loads
    // (write-once buffer; all 4 waves read the same rows -> L1 broadcast).
    f32x4 acc0 = {0.f, 0.f, 0.f, 0.f};
    f32x4 acc1 = {0.f, 0.f, 0.f, 0.f};
    f32x4 acc2 = {0.f, 0.f, 0.f, 0.f};
    f32x4 acc3 = {0.f, 0.f, 0.f, 0.f};
    if (t > 0) {
      const unsigned short* hb = chain_ptr(Zx, hbuf1, chainD, t);
      const unsigned short* ap = hb + arow * 1024 + q * 8;
#pragma unroll
      for (int kt = 0; kt < 8; ++kt) {
        const short8 a0 = *(const short8*)(ap + kt * 32);
        const short8 a1v = *(const short8*)(ap + (kt + 8) * 32);
        const short8 a2v = *(const short8*)(ap + (kt + 16) * 32);
        const short8 a3v = *(const short8*)(ap + (kt + 24) * 32);
        acc0 = MFMA16(a0, Breg[kt], acc0);
        acc1 = MFMA16(a1v, Breg[kt + 8], acc1);
        acc2 = MFMA16(a2v, Breg[kt + 16], acc2);
        acc3 = MFMA16(a3v, Breg[kt + 24], acc3);
      }
    }
    // Transpose through wave-private LDS: C-layout -> (row, unit) lanes.
#pragma unroll
    for (int i = 0; i < 4; ++i)
      zt_w[(q * 4 + i) * 17 + m15] = (acc0[i] + acc1[i]) + (acc2[i] + acc3[i]);
    __builtin_amdgcn_s_waitcnt(0xC07F);   // lgkmcnt(0)
    const float* zr = zt_w + gr * 17 + gu * 4;
    float z0 = zr[0], z1 = zr[1], z2 = zr[2], z3 = zr[3];

    z0 += bf2f((unsigned short)(zx8 >> 0))  + bias0;
    z1 += bf2f((unsigned short)(zx8 >> 16)) + bias1;
    z2 += bf2f((unsigned short)(zx8 >> 32)) + bias2;
    z3 += bf2f((unsigned short)(zx8 >> 48)) + bias3;

    const float ig = sigf(z0);
    const float jg = tanhf_fast(z1);
    const float fg = sigf(z2);
    const float og = sigf(z3);
    cst = fg * cst + ig * jg;
    const float hv = og * tanhf_fast(cst);
    const unsigned short hb16 = f2bf(hv);

    // Pack two adjacent units into one dword; lanes gu=0,2 sc1-store to C_{t+1}.
    const unsigned int partner = (unsigned int)(unsigned short)__shfl_down((int)hb16, 1);
    const unsigned int hpack = (unsigned int)hb16 | (partner << 16);
    if ((gu & 1) == 0) {
      unsigned int* cnxt = (unsigned int*)chain_ptr(Zx, hbuf1, chainD, t + 1);
      __hip_atomic_store(&cnxt[rglob * 512 + Q * 2 + (gu >> 1)], hpack,
                         __ATOMIC_RELAXED, __HIP_MEMORY_SCOPE_AGENT);
    }

    // Drain own sc1 stores to LLC, then leaderless finisher-chain arrival:
    // sub-line add (16/WG line, no pollers); 16th arriver adds super-line;
    // its 4th arriver publishes the domain's 2 go lines.
    COMPILER_FENCE();
    WAIT_VM0();
    COMPILER_FENCE();
    __syncthreads();
    if (tid == 0) {
      const int o1 = __hip_atomic_fetch_add(&a1[(((t + 1) * 4 + d) * 4 + j1) * 16], 1,
                                            __ATOMIC_RELAXED, __HIP_MEMORY_SCOPE_AGENT);
      if (o1 == 15) {
        const int o2 = __hip_atomic_fetch_add(&a2[((t + 1) * 4 + d) * 16], 1,
                                              __ATOMIC_RELAXED, __HIP_MEMORY_SCOPE_AGENT);
        if (o2 == 3) {
          __hip_atomic_store(&go[(((t + 1) * 4 + d) * 2 + 0) * 16], 1,
                             __ATOMIC_RELAXED, __HIP_MEMORY_SCOPE_AGENT);
          __hip_atomic_store(&go[(((t + 1) * 4 + d) * 2 + 1) * 16], 1,
                             __ATOMIC_RELAXED, __HIP_MEMORY_SCOPE_AGENT);
        }
      }
    }
  }
}

// ---------------------------------------------------------------- k4
// Reads decoder h directly from chainD: buffer td = h after step 256+td.
__global__ __launch_bounds__(256, 1)
void k4_proj(const unsigned short* __restrict__ hs,   // = chainD
             const unsigned short* __restrict__ WT,   // WprojT [64][1024]
             const float* __restrict__ b_proj,
             float* __restrict__ out)
{
  __shared__ __align__(16) unsigned short Wl[64 * 264];
  __shared__ float zb[4 * 16 * 68];
  const int tid = threadIdx.x;
  const int wv = tid >> 6, lane = tid & 63;
  const int q = lane >> 4, m = lane & 15;
  const int row0 = blockIdx.x * 64 + wv * 16;
  f32x4 acc[4];
#pragma unroll
  for (int nt = 0; nt < 4; ++nt) acc[nt] = (f32x4){0.f, 0.f, 0.f, 0.f};

  for (int kp = 0; kp < 4; ++kp) {
    __syncthreads();
    for (int i = tid; i < 64 * 32; i += 256) {
      const int n = i >> 5, kc = i & 31;
      *(short8*)(&Wl[n * 264 + kc * 8]) =
          *(const short8*)(WT + (size_t)n * 1024 + kp * 256 + kc * 8);
    }
    __syncthreads();
    const unsigned short* aptr = hs + (size_t)(row0 + m) * 1024 + kp * 256 + q * 8;
#pragma unroll 2
    for (int kt = 0; kt < 8; ++kt) {
      const short8 af = *(const short8*)(aptr + kt * 32);
#pragma unroll
      for (int nt = 0; nt < 4; ++nt) {
        const short8 bfr = *(const short8*)(&Wl[(nt * 16 + m) * 264 + kt * 32 + q * 8]);
        acc[nt] = MFMA16(af, bfr, acc[nt]);
      }
    }
  }
  float* z = &zb[wv * (16 * 68)];
#pragma unroll
  for (int nt = 0; nt < 4; ++nt)
#pragma unroll
    for (int i = 0; i < 4; ++i)
      z[(q * 4 + i) * 68 + nt * 16 + m] = acc[nt][i];
  __syncthreads();
  const int r = lane >> 2, s = lane & 3;
  const float* zrow = z + r * 68 + s * 16;
  float v[16];
  float mx = -1e30f;
#pragma unroll
  for (int j = 0; j < 16; ++j) {
    v[j] = zrow[j] + b_proj[s * 16 + j];
    mx = fmaxf(mx, v[j]);
  }
  mx = fmaxf(mx, __shfl_xor(mx, 1));
  mx = fmaxf(mx, __shfl_xor(mx, 2));
  float sum = 0.f;
#pragma unroll
  for (int j = 0; j < 16; ++j) { v[j] = __expf(v[j] - mx); sum += v[j]; }
  sum += __shfl_xor(sum, 1);
  sum += __shfl_xor(sum, 2);
  const float inv = 1.0f / sum;
  const int nrow = row0 + r;
  const int b = nrow & 63, t = nrow >> 6;
  float* op = out + ((size_t)b * 256 + t) * 64 + s * 16;
#pragma unroll
  for (int x = 0; x < 4; ++x) {
    const float4v o4 = { v[4 * x] * inv, v[4 * x + 1] * inv,
                         v[4 * x + 2] * inv, v[4 * x + 3] * inv };
    *(float4v*)(op + 4 * x) = o4;
  }
}

// ---------------------------------------------------------------- launch
extern "C" void kernel_launch(void* const* d_in, const int* in_sizes, int n_in,
                              void* d_out, int out_size, void* d_ws, size_t ws_size,
                              hipStream_t stream)
{
  const int*   tok_src = (const int*)d_in[0];
  const int*   tok_tgt = (const int*)d_in[1];
  const float* emb_src = (const float*)d_in[2];
  const float* emb_tgt = (const float*)d_in[3];
  const float* W_lstm  = (const float*)d_in[4];
  const float* b_lstm  = (const float*)d_in[5];
  const float* W_proj  = (const float*)d_in[6];
  const float* b_proj  = (const float*)d_in[7];
  float* out = (float*)d_out;

  char* ws = (char*)d_ws;
  size_t off = 0;
  const size_t a1_bytes = (size_t)513 * 4 * 4 * 64;   // sub arrival lines
  const size_t a2_bytes = (size_t)513 * 4 * 64;       // super arrival lines
  const size_t go_bytes = (size_t)513 * 4 * 2 * 64;   // go lines
  int* a1               = (int*)(ws + off);            off += a1_bytes;
  int* a2               = (int*)(ws + off);            off += a2_bytes;
  int* go               = (int*)(ws + off);            off += go_bytes;
  unsigned short* A     = (unsigned short*)(ws + off); off += (size_t)16512 * 512 * 2;
  unsigned short* WT    = (unsigned short*)(ws + off); off += (size_t)4096 * 1536 * 2;
  unsigned short* WPT   = (unsigned short*)(ws + off); off += (size_t)64 * 1024 * 2;
  unsigned short* Zx    = (unsigned short*)(ws + off); off += (size_t)16512 * 4096 * 2;
  unsigned short* hbuf1 = (unsigned short*)(ws + off); off += (size_t)64 * 1024 * 2;
  unsigned short* chainD= (unsigned short*)(ws + off); off += (size_t)256 * 64 * 1024 * 2;
  if (ws_size < off) return;  // insufficient workspace -> loud correctness failure

  hipMemsetAsync(a1, 0, a1_bytes + a2_bytes + go_bytes, stream);
  hipLaunchKernelGGL(k1a_gather, dim3(16512), dim3(128), 0, stream, tok_src, emb_src, emb_tgt, A);
  hipLaunchKernelGGL(k1w_perm,   dim3(3072),  dim3(256), 0, stream, W_lstm, WT);
  hipLaunchKernelGGL(k1p_perm,   dim3(32),    dim3(256), 0, stream, W_proj, WPT);
  hipLaunchKernelGGL(k2_gemm,    dim3(32, 129), dim3(256), 0, stream, A, WT, Zx);
  hipLaunchKernelGGL(k3_rnn,     dim3(256),   dim3(256), 0, stream, Zx, WT, b_lstm, tok_tgt, hbuf1, chainD, a1, a2, go);
  hipLaunchKernelGGL(k4_proj,    dim3(256),   dim3(256), 0, stream, chainD, WPT, b_proj, out);
}